// Round 1
// baseline (2899.778 us; speedup 1.0000x reference)
//
#include <hip/hip_runtime.h>
#include <hip/hip_bf16.h>
#include <stdint.h>
#include <stddef.h>

typedef __attribute__((ext_vector_type(8))) short short8;
typedef __attribute__((ext_vector_type(4))) float f32x4;
typedef __attribute__((ext_vector_type(2))) float f32x2;
typedef __attribute__((ext_vector_type(2))) unsigned int u32x2;

#define NB 512
#define NL 128
#define NFE 33
#define FP 36
#define ND 256
#define NO 16
#define NQ 32      // K-split count
#define KSTEPS 9   // 288 / 32

// ---- static device scratch (rewritten every launch; ~98 MB) ----
__device__ float g_P[2][NQ][2][NB][ND];              // ping-pong partials
__device__ short g_Bpre[2][NQ][KSTEPS][16][64][8];   // frag-major core (bf16 bits)
__device__ short g_BpreOC[8][256][64][8];            // frag-major output_core
__device__ float g_coreT[ND][NFE][ND];               // core transposed (e,f,d)
__device__ float g_Rf[NB][ND];
__device__ short g_Lh[NB][ND];
__device__ short g_Ll[NB][ND];
__device__ float g_T[NB][NO*ND];

__device__ inline unsigned short bf16_rne(float f){
  unsigned int u = __float_as_uint(f);
  unsigned int r = (u + 0x7FFFu + ((u >> 16) & 1u)) >> 16;
  return (unsigned short)r;
}

// ---- core^T: g_coreT[e][f][d] = core[d][f][e] ----
__global__ void k_coreT(const float* __restrict__ core){
  const int bid = blockIdx.x;            // 33*8*8 = 2112
  const int f  = bid % 33;
  const int dt = (bid / 33) & 7;
  const int et = bid / 264;
  __shared__ float tile[32][33];
  const int j  = threadIdx.x & 31;
  const int i0 = threadIdx.x >> 5;
  #pragma unroll
  for (int ii = 0; ii < 4; ii++){
    const int i = i0*4 + ii;
    tile[i][j] = core[((size_t)(dt*32 + i)*33 + f)*256 + et*32 + j];
  }
  __syncthreads();
  #pragma unroll
  for (int ii = 0; ii < 4; ii++){
    const int i = i0*4 + ii;
    g_coreT[et*32 + i][f][dt*32 + j] = tile[j][i];
  }
}

// ---- fragment-major B for both directions ----
__global__ void k_bpre(const float* __restrict__ core){
  const int bid = blockIdx.x;            // 2*32*9 = 576
  const int ks  = bid % 9;
  const int kq  = (bid / 9) & 31;
  const int dir = bid / (9*32);
  const float* src = dir ? &g_coreT[0][0][0] : core;
  const int t = threadIdx.x;             // 512
  const int l = t & 63;
  const int g = l >> 4;
  #pragma unroll
  for (int nn = 0; nn < 2; nn++){
    const int nfrag = (t >> 6)*2 + nn;
    const int n = nfrag*16 + (l & 15);
    short8 v;
    #pragma unroll
    for (int i = 0; i < 8; i++){
      const int kk = ks*32 + g*8 + i;    // 0..287
      const int dl = kk / 36;
      const int f  = kk - dl*36;
      float x = 0.f;
      if (f < 33) x = src[((size_t)(kq*8 + dl)*33 + f)*256 + n];
      v[i] = (short)bf16_rne(x);
    }
    *(short8*)&g_Bpre[dir][kq][ks][nfrag][l][0] = v;
  }
}

// ---- fragment-major output_core ----
__global__ void k_bpreoc(const float* __restrict__ oc){
  const int id = blockIdx.x*256 + threadIdx.x;  // grid 512 -> 131072
  const int l = id & 63;
  const int nfrag = (id >> 6) & 255;
  const int ks = id >> 14;
  const int g = l >> 4;
  short8 v;
  #pragma unroll
  for (int i = 0; i < 8; i++){
    const int d = ks*32 + g*8 + i;
    v[i] = (short)bf16_rne(oc[(size_t)d*4096 + nfrag*16 + (l & 15)]);
  }
  *(short8*)&g_BpreOC[ks][nfrag][l][0] = v;
}

// ---- init P0: q==0 plane = alpha/omega broadcast, rest zero ----
__global__ void k_init(const float* __restrict__ alpha, const float* __restrict__ omega){
  const int id = blockIdx.x*256 + threadIdx.x;  // 8192 blocks
  const int el0 = id * 4;
  const int n0  = el0 & 255;
  const int b   = (el0 >> 8) & 511;
  const int dir = (el0 >> 17) & 1;
  const int q   = el0 >> 18;
  f32x4 v; v[0]=0.f; v[1]=0.f; v[2]=0.f; v[3]=0.f;
  if (q == 0){
    const float* src = dir ? omega : alpha;
    v = *(const f32x4*)(src + n0);
  }
  *(f32x4*)&g_P[0][q][dir][b][n0] = v;
}

// ---- main step: one position of left chain + one of right chain ----
__launch_bounds__(512, 1)
__global__ void k_step(int s, int pb, const float* __restrict__ inputs){
  const int bid  = blockIdx.x;     // 256: bid = bt*64 + (dir*32 + kq)
  const int bt   = bid >> 6;
  const int pair = bid & 63;
  const int dir  = pair >> 5;
  const int kq   = pair & 31;
  const int pos  = dir ? (NL - 1 - s) : s;

  const int t = threadIdx.x;
  const int lane = t & 63;
  const int w  = t >> 6;
  const int wm = w >> 2;   // 0..1
  const int wn = w & 3;    // 0..3

  __shared__ short Ah[3][128][32];
  __shared__ short Al[3][128][32];
  __shared__ float Vlds[128][8];

  // ---- load x row slice into regs ----
  const int m_gen = t >> 2;   // 0..127
  const int fo    = t & 3;
  float xr[12];
  #pragma unroll
  for (int j = 0; j < 12; j++) xr[j] = 0.f;
  {
    const float* xrow = inputs + ((size_t)(bt*128 + m_gen) * NL + pos) * NFE;
    const int fb = fo*8;
    #pragma unroll
    for (int j = 0; j < 8; j++) xr[j] = xrow[fb + j];
    if (fo == 3) xr[8] = xrow[32];
  }

  // ---- stage V tile = sum of 32 partials ----
  {
    const int el = t * 2;
    const int m  = el >> 3;
    const int dl = el & 7;
    const float* Pp = &g_P[pb][0][dir][bt*128 + m][kq*8 + dl];
    float s0 = 0.f, s1 = 0.f;
    #pragma unroll 8
    for (int q = 0; q < NQ; q++){
      f32x2 v = *(const f32x2*)(Pp + (size_t)q * (2*NB*ND));
      s0 += v.x; s1 += v.y;
    }
    Vlds[m][dl] = s0; Vlds[m][dl + 1] = s1;
  }
  __syncthreads();

  float vr[8];
  {
    f32x4 v0 = *(const f32x4*)&Vlds[m_gen][0];
    f32x4 v1 = *(const f32x4*)&Vlds[m_gen][4];
    vr[0]=v0[0]; vr[1]=v0[1]; vr[2]=v0[2]; vr[3]=v0[3];
    vr[4]=v1[0]; vr[5]=v1[1]; vr[6]=v1[2]; vr[7]=v1[3];
  }

  f32x4 acc[4][4];
  #pragma unroll
  for (int i = 0; i < 4; i++)
    #pragma unroll
    for (int j = 0; j < 4; j++){ acc[i][j][0]=0.f; acc[i][j][1]=0.f; acc[i][j][2]=0.f; acc[i][j][3]=0.f; }

  const short* Bp = &g_Bpre[dir][kq][0][0][0][0];

  for (int c = 0; c < 3; c++){
    const int lo = c*96, hi = lo + 96;
    // ---- generate A chunk (hi/lo bf16 split of V*x), swizzled LDS ----
    #pragma unroll
    for (int d = 0; d < 8; d++){
      const float vd = vr[d];
      const int base = d*36 + fo*8;
      const int nch = (fo < 3) ? 2 : 3;
      #pragma unroll
      for (int cc = 0; cc < 3; cc++){
        if (cc >= nch) continue;
        const int kk = base + cc*4;
        if (kk < lo || kk >= hi) continue;
        const float a0 = vd*xr[cc*4+0], a1 = vd*xr[cc*4+1];
        const float a2 = vd*xr[cc*4+2], a3 = vd*xr[cc*4+3];
        const unsigned int u0=__float_as_uint(a0), u1=__float_as_uint(a1);
        const unsigned int u2=__float_as_uint(a2), u3=__float_as_uint(a3);
        u32x2 hv, lv;
        hv.x = (u0 >> 16) | (u1 & 0xFFFF0000u);
        hv.y = (u2 >> 16) | (u3 & 0xFFFF0000u);
        const float r0 = a0 - __uint_as_float(u0 & 0xFFFF0000u);
        const float r1 = a1 - __uint_as_float(u1 & 0xFFFF0000u);
        const float r2 = a2 - __uint_as_float(u2 & 0xFFFF0000u);
        const float r3 = a3 - __uint_as_float(u3 & 0xFFFF0000u);
        lv.x = (__float_as_uint(r0) >> 16) | (__float_as_uint(r1) & 0xFFFF0000u);
        lv.y = (__float_as_uint(r2) >> 16) | (__float_as_uint(r3) & 0xFFFF0000u);
        const int plane = (kk - lo) >> 5;
        const unsigned int byteoff =
          (unsigned int)(m_gen*64 + (kk & 31)*2) ^ (unsigned int)((m_gen & 7) << 4);
        *(u32x2*)((char*)&Ah[plane][0][0] + byteoff) = hv;
        *(u32x2*)((char*)&Al[plane][0][0] + byteoff) = lv;
      }
    }
    __syncthreads();
    // ---- MFMA over 3 k-steps of this chunk ----
    #pragma unroll
    for (int ksl = 0; ksl < 3; ksl++){
      const int ks = c*3 + ksl;
      short8 bfr[4];
      #pragma unroll
      for (int ni = 0; ni < 4; ni++)
        bfr[ni] = *(const short8*)(Bp + (((size_t)(ks*16 + wn*4 + ni))*64 + lane)*8);
      #pragma unroll
      for (int mi = 0; mi < 4; mi++){
        const int m = wm*64 + mi*16 + (lane & 15);
        const unsigned int ro =
          (unsigned int)(m*64 + (lane >> 4)*16) ^ (unsigned int)((m & 7) << 4);
        const short8 ah = *(const short8*)((const char*)&Ah[ksl][0][0] + ro);
        const short8 al = *(const short8*)((const char*)&Al[ksl][0][0] + ro);
        #pragma unroll
        for (int ni = 0; ni < 4; ni++){
          acc[mi][ni] = __builtin_amdgcn_mfma_f32_16x16x32_bf16(ah, bfr[ni], acc[mi][ni], 0, 0, 0);
          acc[mi][ni] = __builtin_amdgcn_mfma_f32_16x16x32_bf16(al, bfr[ni], acc[mi][ni], 0, 0, 0);
        }
      }
    }
    __syncthreads();
  }

  // ---- write fp32 partial tile ----
  const int nb = pb ^ 1;
  #pragma unroll
  for (int mi = 0; mi < 4; mi++){
    const int row0 = bt*128 + wm*64 + mi*16 + ((lane >> 4) << 2);
    #pragma unroll
    for (int ni = 0; ni < 4; ni++){
      const int n = wn*64 + ni*16 + (lane & 15);
      float* dst = &g_P[nb][kq][dir][row0][n];
      #pragma unroll
      for (int r = 0; r < 4; r++) dst[(size_t)r*ND] = acc[mi][ni][r];
    }
  }
}

// ---- reduce partials into boundary vectors; split L into bf16 hi/lo ----
__global__ void k_lr(int pb){
  const int id = blockIdx.x*256 + threadIdx.x;  // 1024 blocks
  const int n = id & 255;
  const int b = (id >> 8) & 511;
  const int dir = id >> 17;
  float s = 0.f;
  #pragma unroll 8
  for (int q = 0; q < NQ; q++) s += g_P[pb][q][dir][b][n];
  if (dir == 0){
    const unsigned int u = __float_as_uint(s);
    g_Lh[b][n] = (short)(u >> 16);
    const float r = s - __uint_as_float(u & 0xFFFF0000u);
    g_Ll[b][n] = (short)(__float_as_uint(r) >> 16);
  } else {
    g_Rf[b][n] = s;
  }
}

// ---- T[b, (o,e)] = sum_d L[b,d] * oc[d,(o,e)] ----
__launch_bounds__(512, 1)
__global__ void k_gemm1(){
  const int bt = blockIdx.x >> 5;   // 4
  const int nt = blockIdx.x & 31;   // 32
  const int t = threadIdx.x, lane = t & 63;
  const int w = t >> 6, wm = w >> 2, wn = w & 3;
  f32x4 acc[4][2];
  #pragma unroll
  for (int i = 0; i < 4; i++)
    #pragma unroll
    for (int j = 0; j < 2; j++){ acc[i][j][0]=0.f; acc[i][j][1]=0.f; acc[i][j][2]=0.f; acc[i][j][3]=0.f; }
  #pragma unroll
  for (int ks = 0; ks < 8; ks++){
    short8 bfr[2];
    #pragma unroll
    for (int ni = 0; ni < 2; ni++)
      bfr[ni] = *(const short8*)&g_BpreOC[ks][nt*8 + wn*2 + ni][lane][0];
    const int k0 = ks*32 + (lane >> 4)*8;
    #pragma unroll
    for (int mi = 0; mi < 4; mi++){
      const int bm = bt*128 + wm*64 + mi*16 + (lane & 15);
      const short8 ah = *(const short8*)&g_Lh[bm][k0];
      const short8 al = *(const short8*)&g_Ll[bm][k0];
      #pragma unroll
      for (int ni = 0; ni < 2; ni++){
        acc[mi][ni] = __builtin_amdgcn_mfma_f32_16x16x32_bf16(ah, bfr[ni], acc[mi][ni], 0, 0, 0);
        acc[mi][ni] = __builtin_amdgcn_mfma_f32_16x16x32_bf16(al, bfr[ni], acc[mi][ni], 0, 0, 0);
      }
    }
  }
  #pragma unroll
  for (int mi = 0; mi < 4; mi++){
    const int row0 = bt*128 + wm*64 + mi*16 + ((lane >> 4) << 2);
    #pragma unroll
    for (int ni = 0; ni < 2; ni++){
      const int n = nt*128 + wn*32 + ni*16 + (lane & 15);
      #pragma unroll
      for (int r = 0; r < 4; r++) g_T[row0 + r][n] = acc[mi][ni][r];
    }
  }
}

// ---- out[b,o] = sum_e T[b,(o,e)] * R[b,e] ----
__global__ void k_out(float* __restrict__ out){
  const int b0 = blockIdx.x * 8;    // 64 blocks
  __shared__ float Rl[8][256];
  const int t = threadIdx.x;
  for (int i = t; i < 2048; i += 256)
    Rl[i >> 8][i & 255] = g_Rf[b0 + (i >> 8)][i & 255];
  __syncthreads();
  const int bl = t >> 5;
  const int o  = (t >> 1) & 15;
  const int eh = t & 1;
  const float* Trow = &g_T[b0 + bl][o*256 + eh*128];
  const float* Rr = &Rl[bl][eh*128];
  float acc = 0.f;
  #pragma unroll 8
  for (int e4 = 0; e4 < 32; e4++){
    const f32x4 tv = *(const f32x4*)(Trow + e4*4);
    const f32x4 rv = *(const f32x4*)(Rr + e4*4);
    acc += tv[0]*rv[0] + tv[1]*rv[1] + tv[2]*rv[2] + tv[3]*rv[3];
  }
  acc += __shfl_xor(acc, 1);
  if (eh == 0) out[(b0 + bl)*16 + o] = acc;
}

extern "C" void kernel_launch(void* const* d_in, const int* in_sizes, int n_in,
                              void* d_out, int out_size, void* d_ws, size_t ws_size,
                              hipStream_t stream){
  const float* inputs = (const float*)d_in[0];
  const float* core   = (const float*)d_in[1];
  const float* alpha  = (const float*)d_in[2];
  const float* omega  = (const float*)d_in[3];
  const float* oc     = (const float*)d_in[4];
  float* out = (float*)d_out;
  (void)in_sizes; (void)n_in; (void)out_size; (void)d_ws; (void)ws_size;

  k_coreT <<<dim3(2112), dim3(256), 0, stream>>>(core);
  k_bpre  <<<dim3(576),  dim3(512), 0, stream>>>(core);
  k_bpreoc<<<dim3(512),  dim3(256), 0, stream>>>(oc);
  k_init  <<<dim3(8192), dim3(256), 0, stream>>>(alpha, omega);
  for (int s = 0; s < 64; s++)
    k_step<<<dim3(256), dim3(512), 0, stream>>>(s, s & 1, inputs);
  k_lr    <<<dim3(1024), dim3(256), 0, stream>>>(0);
  k_gemm1 <<<dim3(128),  dim3(512), 0, stream>>>();
  k_out   <<<dim3(64),   dim3(256), 0, stream>>>(out);
}

// Round 2
// 1048.569 us; speedup vs baseline: 2.7655x; 2.7655x over previous
//
#include <hip/hip_runtime.h>
#include <hip/hip_bf16.h>
#include <stdint.h>
#include <stddef.h>

typedef __attribute__((ext_vector_type(8))) short short8;
typedef __attribute__((ext_vector_type(4))) float f32x4;
typedef __attribute__((ext_vector_type(4))) unsigned int u32x4;
typedef __attribute__((ext_vector_type(4))) unsigned short u16x4;

#define NB 512
#define NL 128
#define ND 256
#define NO 16
#define KQ 8      // K-split planes (d-chunks of 32)
#define NTN 2     // N-split (tiles of 128)
#define BTN 8     // M-split (tiles of 64)

// ---- static device scratch ----
// Exact fp32 boundary-vector carrier (identity bypass), ping-pong by parity.
__device__ __attribute__((aligned(16))) float g_Vb[2][2][NB][ND];
// bf16 correction partials: [parity][kq][dir][b][n]
__device__ __attribute__((aligned(16))) unsigned short g_Pc[2][KQ][2][NB][ND];
// fragment-major B (core / core^T), ks dim padded 32->34 for branchless prefetch
__device__ __attribute__((aligned(16))) short g_Bf[2][KQ][NTN][34][8][64][8];
// repacked inputs: x[b][pos][f-1], f=1..32 (128B rows, aligned)
__device__ __attribute__((aligned(16))) float g_xr[NB][NL][32];
// output-core fragments + final-stage buffers (same as round 1)
__device__ __attribute__((aligned(16))) short g_BpreOC[8][256][64][8];
__device__ __attribute__((aligned(16))) float g_Rf[NB][ND];
__device__ __attribute__((aligned(16))) short g_Lh[NB][ND];
__device__ __attribute__((aligned(16))) short g_Ll[NB][ND];
__device__ __attribute__((aligned(16))) float g_T[NB][NO*ND];

__device__ inline unsigned short bf16_rne(float f){
  unsigned int u = __float_as_uint(f);
  unsigned int r = (u + 0x7FFFu + ((u >> 16) & 1u)) >> 16;
  return (unsigned short)r;
}
__device__ inline float b2f(unsigned short u){
  return __uint_as_float((unsigned int)u << 16);
}
__device__ inline unsigned short f2bf(float f){
  __hip_bfloat16 h = __float2bfloat16(f);
  unsigned short u; __builtin_memcpy(&u, &h, 2); return u;
}
__device__ inline unsigned int pk2(float a, float b){
  __hip_bfloat162 h = __float22bfloat162_rn(make_float2(a, b));
  unsigned int u; __builtin_memcpy(&u, &h, 4); return u;
}
__device__ inline f32x4 z4(){ f32x4 v; v[0]=0.f; v[1]=0.f; v[2]=0.f; v[3]=0.f; return v; }

// A-fragment: bf16(vm * x[i]) for i=0..7 (one V scalar times 8 x regs)
__device__ inline short8 genA(float vm, const f32x4 xa, const f32x4 xb){
  u32x4 u;
  u[0] = pk2(vm*xa[0], vm*xa[1]);
  u[1] = pk2(vm*xa[2], vm*xa[3]);
  u[2] = pk2(vm*xb[0], vm*xb[1]);
  u[3] = pk2(vm*xb[2], vm*xb[3]);
  return __builtin_bit_cast(short8, u);
}

// ---- B fragments for both directions (one-time) ----
// dir0: B[k=(dl,fi)][n] = core[dl][fi+1][n]; dir1: = core[n][fi+1][dl]
__global__ void k_bf(const float* __restrict__ core){
  const int id = blockIdx.x*512 + threadIdx.x;   // 2*8*2*32*8*64 = 524288
  const int l   = id & 63;
  const int nf  = (id >> 6) & 7;
  const int ks  = (id >> 9) & 31;
  const int nt  = (id >> 14) & 1;
  const int kq  = (id >> 15) & 7;
  const int dir = (id >> 18) & 1;
  const int n_g = nt*128 + nf*16 + (l & 15);
  const int dl  = kq*32 + ks;
  short8 v;
  #pragma unroll
  for (int i = 0; i < 8; i++){
    const int f = (l >> 4)*8 + i + 1;
    const float x = dir ? core[((size_t)n_g*33 + f)*256 + dl]
                        : core[((size_t)dl*33 + f)*256 + n_g];
    v[i] = (short)bf16_rne(x);
  }
  *(short8*)&g_Bf[dir][kq][nt][ks][nf][l][0] = v;
}

// ---- fragment-major output_core (one-time) ----
__global__ void k_bpreoc(const float* __restrict__ oc){
  const int id = blockIdx.x*256 + threadIdx.x;  // 512 blocks -> 131072
  const int l = id & 63;
  const int nfrag = (id >> 6) & 255;
  const int ks = id >> 14;
  const int g = l >> 4;
  short8 v;
  #pragma unroll
  for (int i = 0; i < 8; i++){
    const int d = ks*32 + g*8 + i;
    v[i] = (short)bf16_rne(oc[(size_t)d*4096 + nfrag*16 + (l & 15)]);
  }
  *(short8*)&g_BpreOC[ks][nfrag][l][0] = v;
}

// ---- repack inputs, dropping bias channel ----
__global__ void k_xr(const float* __restrict__ inputs){
  const int id = blockIdx.x*256 + threadIdx.x;  // 512*128*8 = 524288
  const int j = id & 7;
  const int pos = (id >> 3) & 127;
  const int b = id >> 10;
  const float* src = inputs + ((size_t)b*128 + pos)*33 + 1 + j*4;
  f32x4 v; v[0]=src[0]; v[1]=src[1]; v[2]=src[2]; v[3]=src[3];
  *(f32x4*)&g_xr[b][pos][j*4] = v;
}

// ---- init: Vb[0] = alpha/omega, Pc[0] = 0 ----
__global__ void k_init(const float* __restrict__ alpha, const float* __restrict__ omega){
  const int id = blockIdx.x*256 + threadIdx.x;  // 262144
  const int n = id & 255;
  const int b = (id >> 8) & 511;
  const int dir = id >> 17;
  g_Vb[0][dir][b][n] = dir ? omega[n] : alpha[n];
  short8 z; 
  #pragma unroll
  for (int i = 0; i < 8; i++) z[i] = 0;
  ((short8*)&g_Pc[0][0][0][0][0])[id] = z;  // 8*2*512*256/8 = 262144 short8
}

// ---- main step: V_s = Vb + sum_q Pc; write Vb_next (nt==0); MFMA corrections ----
__launch_bounds__(512, 1)
__global__ void k_step(int s){
  const int bid = blockIdx.x;          // 256
  const int xw = bid & 7, r = bid >> 3;
  const int sl = xw + ((r & 3) << 3);  // slice 0..31: (dir,kq,nt); same-slice bt's share XCD
  const int bt = r >> 2;
  const int dir = sl >> 4, kq = (sl >> 1) & 7, nt = sl & 1;
  const int pos = dir ? (127 - s) : s;
  const int pp = s & 1, np = pp ^ 1;

  __shared__ float Vl[34][66];   // [local d][local m], stride 66 breaks bank aliasing

  const int t = threadIdx.x;
  // ---- staging: V tile = Vb + sum of 8 bf16 partials ----
  {
    const int m_s = t >> 3;
    const int d0 = (t & 7) << 2;
    const int row_s = bt*64 + m_s;
    f32x4 v = *(const f32x4*)&g_Vb[pp][dir][row_s][kq*32 + d0];
    const unsigned short* pc = &g_Pc[pp][0][dir][row_s][kq*32 + d0];
    #pragma unroll
    for (int q = 0; q < 8; q++){
      u16x4 c = *(const u16x4*)(pc + (size_t)q * (2*NB*ND));
      v[0] += b2f(c[0]); v[1] += b2f(c[1]); v[2] += b2f(c[2]); v[3] += b2f(c[3]);
    }
    Vl[d0+0][m_s] = v[0]; Vl[d0+1][m_s] = v[1];
    Vl[d0+2][m_s] = v[2]; Vl[d0+3][m_s] = v[3];
    if (nt == 0) *(f32x4*)&g_Vb[np][dir][row_s][kq*32 + d0] = v;  // exact bypass carry
  }

  const int lane = t & 63, w = t >> 6;
  const int wm = w & 3, wn = w >> 2;         // 4 m-pos x 2 n-pos; wave tile 16x64
  const int ml = wm*16 + (lane & 15);
  const int row = bt*64 + ml;
  const int g = lane >> 4;
  const f32x4 xa = *(const f32x4*)&g_xr[row][pos][g*8];
  const f32x4 xb = *(const f32x4*)&g_xr[row][pos][g*8 + 4];

  __syncthreads();

  // ---- MFMA over 32 ksteps (d-chunk), B double-buffered in regs ----
  const short8* Bp = (const short8*)&g_Bf[dir][kq][nt][0][0][0][0];
  const int boff = (wn*4)*64 + lane;
  short8 bc[4], bn[4];
  {
    const short8* p = Bp + boff;
    #pragma unroll
    for (int ni = 0; ni < 4; ni++) bc[ni] = p[ni*64];
    p += 512;
    #pragma unroll
    for (int ni = 0; ni < 4; ni++) bn[ni] = p[ni*64];
  }
  float v0 = Vl[0][ml], v1 = Vl[1][ml];
  f32x4 ac[4] = { z4(), z4(), z4(), z4() };

  for (int ks = 0; ks < 32; ks += 2){
    const float v2 = Vl[ks+2][ml];       // padded rows 32/33: read-only junk
    const float v3 = Vl[ks+3][ml];
    const short8 a0 = genA(v0, xa, xb);
    #pragma unroll
    for (int ni = 0; ni < 4; ni++)
      ac[ni] = __builtin_amdgcn_mfma_f32_16x16x32_bf16(a0, bc[ni], ac[ni], 0, 0, 0);
    {
      const short8* p = Bp + (ks+2)*512 + boff;   // padded ks 32/33: junk, unused
      #pragma unroll
      for (int ni = 0; ni < 4; ni++) bc[ni] = p[ni*64];
    }
    const short8 a1 = genA(v1, xa, xb);
    #pragma unroll
    for (int ni = 0; ni < 4; ni++)
      ac[ni] = __builtin_amdgcn_mfma_f32_16x16x32_bf16(a1, bn[ni], ac[ni], 0, 0, 0);
    {
      const short8* p = Bp + (ks+3)*512 + boff;
      #pragma unroll
      for (int ni = 0; ni < 4; ni++) bn[ni] = p[ni*64];
    }
    v0 = v2; v1 = v3;
  }

  // ---- write bf16 correction partials ----
  const int row_o0 = bt*64 + wm*16 + ((lane >> 4) << 2);
  const int n_o0 = nt*128 + wn*64 + (lane & 15);
  #pragma unroll
  for (int ni = 0; ni < 4; ni++)
    #pragma unroll
    for (int rr = 0; rr < 4; rr++)
      g_Pc[np][kq][dir][row_o0 + rr][n_o0 + ni*16] = f2bf(ac[ni][rr]);
}

// ---- final boundary vectors; L split hi/lo bf16 for the output GEMM ----
__global__ void k_lr(){
  const int id = blockIdx.x*256 + threadIdx.x;  // 262144
  const int n = id & 255;
  const int b = (id >> 8) & 511;
  const int dir = id >> 17;
  float s = g_Vb[0][dir][b][n];
  #pragma unroll
  for (int q = 0; q < 8; q++) s += b2f(g_Pc[0][q][dir][b][n]);
  if (dir == 0){
    const unsigned int u = __float_as_uint(s);
    g_Lh[b][n] = (short)(u >> 16);
    const float rr = s - __uint_as_float(u & 0xFFFF0000u);
    g_Ll[b][n] = (short)(__float_as_uint(rr) >> 16);
  } else {
    g_Rf[b][n] = s;
  }
}

// ---- T[b,(o,e)] = sum_d L[b,d] * oc[d,(o,e)] ----
__launch_bounds__(512, 1)
__global__ void k_gemm1(){
  const int bt = blockIdx.x >> 5;   // 4
  const int nt = blockIdx.x & 31;   // 32
  const int t = threadIdx.x, lane = t & 63;
  const int w = t >> 6, wm = w >> 2, wn = w & 3;
  f32x4 acc[4][2];
  #pragma unroll
  for (int i = 0; i < 4; i++)
    #pragma unroll
    for (int j = 0; j < 2; j++) acc[i][j] = z4();
  #pragma unroll
  for (int ks = 0; ks < 8; ks++){
    short8 bfr[2];
    #pragma unroll
    for (int ni = 0; ni < 2; ni++)
      bfr[ni] = *(const short8*)&g_BpreOC[ks][nt*8 + wn*2 + ni][lane][0];
    const int k0 = ks*32 + (lane >> 4)*8;
    #pragma unroll
    for (int mi = 0; mi < 4; mi++){
      const int bm = bt*128 + wm*64 + mi*16 + (lane & 15);
      const short8 ah = *(const short8*)&g_Lh[bm][k0];
      const short8 al = *(const short8*)&g_Ll[bm][k0];
      #pragma unroll
      for (int ni = 0; ni < 2; ni++){
        acc[mi][ni] = __builtin_amdgcn_mfma_f32_16x16x32_bf16(ah, bfr[ni], acc[mi][ni], 0, 0, 0);
        acc[mi][ni] = __builtin_amdgcn_mfma_f32_16x16x32_bf16(al, bfr[ni], acc[mi][ni], 0, 0, 0);
      }
    }
  }
  #pragma unroll
  for (int mi = 0; mi < 4; mi++){
    const int row0 = bt*128 + wm*64 + mi*16 + ((lane >> 4) << 2);
    #pragma unroll
    for (int ni = 0; ni < 2; ni++){
      const int n = nt*128 + wn*32 + ni*16 + (lane & 15);
      #pragma unroll
      for (int r = 0; r < 4; r++) g_T[row0 + r][n] = acc[mi][ni][r];
    }
  }
}

// ---- out[b,o] = sum_e T[b,(o,e)] * R[b,e] ----
__global__ void k_out(float* __restrict__ out){
  const int b0 = blockIdx.x * 8;    // 64 blocks
  __shared__ float Rl[8][256];
  const int t = threadIdx.x;
  for (int i = t; i < 2048; i += 256)
    Rl[i >> 8][i & 255] = g_Rf[b0 + (i >> 8)][i & 255];
  __syncthreads();
  const int bl = t >> 5;
  const int o  = (t >> 1) & 15;
  const int eh = t & 1;
  const float* Trow = &g_T[b0 + bl][o*256 + eh*128];
  const float* Rr = &Rl[bl][eh*128];
  float acc = 0.f;
  #pragma unroll 8
  for (int e4 = 0; e4 < 32; e4++){
    const f32x4 tv = *(const f32x4*)(Trow + e4*4);
    const f32x4 rv = *(const f32x4*)(Rr + e4*4);
    acc += tv[0]*rv[0] + tv[1]*rv[1] + tv[2]*rv[2] + tv[3]*rv[3];
  }
  acc += __shfl_xor(acc, 1);
  if (eh == 0) out[(b0 + bl)*16 + o] = acc;
}

extern "C" void kernel_launch(void* const* d_in, const int* in_sizes, int n_in,
                              void* d_out, int out_size, void* d_ws, size_t ws_size,
                              hipStream_t stream){
  const float* inputs = (const float*)d_in[0];
  const float* core   = (const float*)d_in[1];
  const float* alpha  = (const float*)d_in[2];
  const float* omega  = (const float*)d_in[3];
  const float* oc     = (const float*)d_in[4];
  float* out = (float*)d_out;
  (void)in_sizes; (void)n_in; (void)out_size; (void)d_ws; (void)ws_size;

  k_bf    <<<dim3(1024), dim3(512), 0, stream>>>(core);
  k_bpreoc<<<dim3(512),  dim3(256), 0, stream>>>(oc);
  k_xr    <<<dim3(2048), dim3(256), 0, stream>>>(inputs);
  k_init  <<<dim3(1024), dim3(256), 0, stream>>>(alpha, omega);
  for (int s = 0; s < 64; s++)
    k_step<<<dim3(256), dim3(512), 0, stream>>>(s);
  k_lr    <<<dim3(1024), dim3(256), 0, stream>>>();
  k_gemm1 <<<dim3(128),  dim3(512), 0, stream>>>();
  k_out   <<<dim3(64),   dim3(256), 0, stream>>>(out);
}